// Round 1
// baseline (28174.228 us; speedup 1.0000x reference)
//
#include <hip/hip_runtime.h>
#include <math.h>

// ConvLSTMClassifier: B=64, CH=128, H(time)=128, W=512, NC=10
// Height-1 strips + SAME padding => only ky=1 of the 3x3 kernel matters.
// Per step: gates[b,oc,w] = bias[oc] + sum_ic sum_kx combined[b,ic,w+kx-1]*Wt[oc,ic,1,kx]
//   combined ch0 = x row, ch 1..128 = h.
// Fused step kernel: conv + sigmoid/tanh + c/h update. 128 sequential launches.

constexpr int kB  = 64;
constexpr int kCH = 128;
constexpr int kH  = 128;
constexpr int kW  = 512;
constexpr int kNC = 10;

// ---------------------------------------------------------------------------
// Weight repack: pw[ic][ch*4+g][kx] (ic = h-channel 0..127), pxw[ch*4+g][kx],
// pb[ch*4+g]. g: 0=i,1=f,2=g,3=o (oc = g*128+ch). Makes each wave's weight
// slice contiguous for scalar (s_load) fetch.
// ---------------------------------------------------------------------------
__global__ __launch_bounds__(256) void pack_weights(
    const float* __restrict__ conv_w,  // [512][129][3][3]
    const float* __restrict__ conv_b,  // [512]
    float* __restrict__ pw,            // [128][512][3]
    float* __restrict__ pxw,           // [512][3]
    float* __restrict__ pb)            // [512]
{
    int idx = blockIdx.x * 256 + threadIdx.x;
    const int total = 512 * 129 * 3;
    if (idx < total) {
        int kx    = idx % 3;
        int rest  = idx / 3;
        int ic129 = rest % 129;
        int oc    = rest / 129;
        int ch = oc & 127;
        int g  = oc >> 7;
        int ocp = ch * 4 + g;
        float v = conv_w[((size_t)(oc * 129 + ic129) * 3 + 1) * 3 + kx];
        if (ic129 == 0) {
            pxw[ocp * 3 + kx] = v;
        } else {
            pw[(size_t)(ic129 - 1) * 1536 + ocp * 3 + kx] = v;
        }
    }
    if (idx < 512) {
        int ch = idx & 127, g = idx >> 7;
        pb[ch * 4 + g] = conv_b[idx];
    }
}

__device__ __forceinline__ float fsig(float v) {
    return 1.0f / (1.0f + __expf(-v));
}
__device__ __forceinline__ float ftanh(float v) {
    float e = __expf(2.0f * v);
    return 1.0f - 2.0f / (e + 1.0f);
}

// ---------------------------------------------------------------------------
// One LSTM step. grid = (W/64, CH/32, B), block = 256 (4 waves).
// lane = w position (coalesced h loads); each wave owns 8 channels
// (ch0..ch0+7), computing all 4 gates for each -> 32 fp32 accumulators.
// Weights are wave-uniform -> scalar loads (ch0 forced into SGPR).
// ---------------------------------------------------------------------------
template <bool FIRST>
__global__ __launch_bounds__(256) void lstm_step(
    const float* __restrict__ x,    // [B][1][H][W]
    const float* __restrict__ pw,   // [128][512][3]
    const float* __restrict__ pxw,  // [512][3]
    const float* __restrict__ pb,   // [512]
    const float* __restrict__ h_prev,  // [B][CH][W]
    float* __restrict__ h_next,        // [B][CH][W]
    float* __restrict__ c,             // [B][CH][W] (in-place)
    int t)
{
    const int lane = threadIdx.x & 63;
    const int wave = threadIdx.x >> 6;
    const int w    = blockIdx.x * 64 + lane;
    const int b    = blockIdx.z;
    const int ch0  = __builtin_amdgcn_readfirstlane(blockIdx.y * 32 + wave * 8);

    const int wm = (w > 0) ? (w - 1) : 0;          // clamped (always in-bounds)
    const int wp = (w < kW - 1) ? (w + 1) : (kW - 1);

    float acc[8][4];
    {
        const float* pbp = pb + ch0 * 4;
#pragma unroll
        for (int cc = 0; cc < 8; ++cc)
#pragma unroll
            for (int g = 0; g < 4; ++g)
                acc[cc][g] = pbp[cc * 4 + g];
    }

    // x contribution (combined channel 0)
    {
        const float* xrow = x + ((size_t)b * kH + t) * kW;
        float xm = xrow[wm]; xm = (w > 0) ? xm : 0.0f;
        float xc = xrow[w];
        float xp = xrow[wp]; xp = (w < kW - 1) ? xp : 0.0f;
        const float* wr0 = pxw + ch0 * 12;
#pragma unroll
        for (int cc = 0; cc < 8; ++cc)
#pragma unroll
            for (int g = 0; g < 4; ++g) {
                const float* wr = wr0 + (cc * 4 + g) * 3;
                acc[cc][g] = fmaf(wr[0], xm, acc[cc][g]);
                acc[cc][g] = fmaf(wr[1], xc, acc[cc][g]);
                acc[cc][g] = fmaf(wr[2], xp, acc[cc][g]);
            }
    }

    // h contribution (combined channels 1..128)
    if (!FIRST) {
        const float* hb = h_prev + (size_t)b * kCH * kW;
        for (int ic = 0; ic < kCH; ++ic) {
            const float* hrow = hb + (size_t)ic * kW;
            float hm = hrow[wm]; hm = (w > 0) ? hm : 0.0f;
            float hc = hrow[w];
            float hp = hrow[wp]; hp = (w < kW - 1) ? hp : 0.0f;
            const float* wr0 = pw + (size_t)ic * 1536 + ch0 * 12;
#pragma unroll
            for (int cc = 0; cc < 8; ++cc)
#pragma unroll
                for (int g = 0; g < 4; ++g) {
                    const float* wr = wr0 + (cc * 4 + g) * 3;
                    acc[cc][g] = fmaf(wr[0], hm, acc[cc][g]);
                    acc[cc][g] = fmaf(wr[1], hc, acc[cc][g]);
                    acc[cc][g] = fmaf(wr[2], hp, acc[cc][g]);
                }
        }
    }

    // elementwise gate nonlinearities + state update
#pragma unroll
    for (int cc = 0; cc < 8; ++cc) {
        size_t idx = ((size_t)b * kCH + (ch0 + cc)) * kW + w;
        float cprev = FIRST ? 0.0f : c[idx];
        float si = fsig(acc[cc][0]);
        float sf = fsig(acc[cc][1]);
        float tg = ftanh(acc[cc][2]);
        float so = fsig(acc[cc][3]);
        float cn = sf * cprev + si * tg;
        float hn = so * ftanh(cn);
        c[idx] = cn;
        h_next[idx] = hn;
    }
}

// ---------------------------------------------------------------------------
// Mean over W + Linear(CH->NC). grid = B, block = 128 (thread = channel).
// ---------------------------------------------------------------------------
__global__ __launch_bounds__(128) void pool_fc(
    const float* __restrict__ h,     // [B][CH][W] final hidden
    const float* __restrict__ fc_w,  // [NC][CH]
    const float* __restrict__ fc_b,  // [NC]
    float* __restrict__ out)         // [B][NC]
{
    __shared__ float pooled[kCH];
    const int b = blockIdx.x;
    const int ch = threadIdx.x;
    const float4* row = (const float4*)(h + ((size_t)b * kCH + ch) * kW);
    float s = 0.0f;
#pragma unroll 8
    for (int i = 0; i < kW / 4; ++i) {
        float4 v = row[i];
        s += v.x + v.y + v.z + v.w;
    }
    pooled[ch] = s * (1.0f / kW);
    __syncthreads();
    if (ch < kNC) {
        float a = fc_b[ch];
        for (int k = 0; k < kCH; ++k)
            a = fmaf(pooled[k], fc_w[ch * kCH + k], a);
        out[b * kNC + ch] = a;
    }
}

// ---------------------------------------------------------------------------
extern "C" void kernel_launch(void* const* d_in, const int* in_sizes, int n_in,
                              void* d_out, int out_size, void* d_ws, size_t ws_size,
                              hipStream_t stream) {
    const float* x      = (const float*)d_in[0];
    const float* conv_w = (const float*)d_in[1];
    const float* conv_b = (const float*)d_in[2];
    const float* fc_w   = (const float*)d_in[3];
    const float* fc_b   = (const float*)d_in[4];
    float* out = (float*)d_out;

    const size_t stateN = (size_t)kB * kCH * kW;  // 4,194,304 floats
    float* hA  = (float*)d_ws;
    float* hB  = hA + stateN;
    float* c   = hB + stateN;
    float* pw  = c + stateN;          // 128*512*3 = 196,608
    float* pxw = pw + 128 * 512 * 3;  // 1536
    float* pb  = pxw + 1536;          // 512

    {
        const int total = 512 * 129 * 3;
        pack_weights<<<(total + 255) / 256, 256, 0, stream>>>(conv_w, conv_b, pw, pxw, pb);
    }

    dim3 grid(kW / 64, kCH / 32, kB);
    dim3 block(256);
    // t=0: h_prev/c treated as zero; writes hB, c.
    lstm_step<true><<<grid, block, 0, stream>>>(x, pw, pxw, pb, hA, hB, c, 0);
    for (int t = 1; t < kH; ++t) {
        float* hp = (t & 1) ? hB : hA;
        float* hn = (t & 1) ? hA : hB;
        lstm_step<false><<<grid, block, 0, stream>>>(x, pw, pxw, pb, hp, hn, c, t);
    }
    // t=127 (odd) wrote hA.
    pool_fc<<<kB, 128, 0, stream>>>(hA, fc_w, fc_b, out);
}

// Round 2
// 4743.864 us; speedup vs baseline: 5.9391x; 5.9391x over previous
//
#include <hip/hip_runtime.h>
#include <hip/hip_bf16.h>
#include <math.h>

// ConvLSTMClassifier on MI355X — MFMA version.
// Per step t: gates[b,w,n] = bias[n] + sum_kx x[b,t,w+kx-1]*pxw[kx,n]
//                          + sum_kx sum_ic h[b,w+kx-1,ic]*Bp[kx,ic,n]
// n = oc = g*128+ch (gate-major, matches jnp.split order).
// h stored channel-last bf16 [B][W][CH]; c fp32 same layout.
// Block: 256 thr / 4 waves; tile M=64 (w), N=256 (4 gates x 64 ch).
// Wave: M=64 (4 mfrags) x 16 ch x 4 gates (one 16x16 frag per gate).
// A staged in LDS (XOR-swizzled vs 16-way bank conflict); B direct from L2.

constexpr int kB  = 64;
constexpr int kCH = 128;
constexpr int kH  = 128;
constexpr int kW  = 512;
constexpr int kNC = 10;

typedef __attribute__((ext_vector_type(8))) short short8v;
typedef __attribute__((ext_vector_type(4))) float float4v;

__device__ __forceinline__ float fsig(float v) {
    return 1.0f / (1.0f + __expf(-v));
}
__device__ __forceinline__ float ftanh(float v) {
    float e = __expf(2.0f * v);
    return 1.0f - 2.0f / (e + 1.0f);
}

// ---------------------------------------------------------------------------
// Weight pack: Bp[kx][oc][ic] bf16 (k-contig for B-frag 16B loads),
// pxw[kx][oc] f32 (x-channel weights), pb[oc] f32.
// ---------------------------------------------------------------------------
__global__ __launch_bounds__(256) void pack_weights(
    const float* __restrict__ conv_w,  // [512][129][3][3]
    const float* __restrict__ conv_b,  // [512]
    short* __restrict__ Bp,            // [3][512][128]
    float* __restrict__ pxw,           // [3][512]
    float* __restrict__ pb)            // [512]
{
    int idx = blockIdx.x * 256 + threadIdx.x;
    if (idx < 3 * 512 * 128) {
        int ic = idx & 127;
        int oc = (idx >> 7) & 511;
        int kx = idx >> 16;  // 512*128 = 65536
        float v = conv_w[((oc * 129 + 1 + ic) * 3 + 1) * 3 + kx];
        __hip_bfloat16 hv = __float2bfloat16(v);
        Bp[idx] = *reinterpret_cast<short*>(&hv);
    }
    if (idx < 3 * 512) {
        int oc = idx & 511, kx = idx >> 9;
        pxw[idx] = conv_w[((oc * 129 + 0) * 3 + 1) * 3 + kx];
    }
    if (idx < 512) pb[idx] = conv_b[idx];
}

// ---------------------------------------------------------------------------
// One LSTM step, MFMA. grid = (8 mtiles, 2 chtiles, 64 b), block = 256.
// ---------------------------------------------------------------------------
template <bool FIRST>
__global__ __launch_bounds__(256, 4) void lstm_step(
    const float* __restrict__ x,          // [B][1][H][W]
    const short* __restrict__ Bp,         // [3][512][128] bf16 bits
    const float* __restrict__ pxw,        // [3][512]
    const float* __restrict__ pb,         // [512]
    const __hip_bfloat16* __restrict__ hprev,  // [B][W][CH]
    __hip_bfloat16* __restrict__ hnext,        // [B][W][CH]
    float* __restrict__ c,                     // [B][W][CH]
    int t)
{
    __shared__ alignas(16) short Alds[66 * 128];  // 66 rows x 256B, swizzled
    __shared__ float xs[66];

    const int tid  = threadIdx.x;
    const int lane = tid & 63;
    const int wave = tid >> 6;
    const int w0   = blockIdx.x * 64;
    const int cht  = blockIdx.y;
    const int b    = blockIdx.z;

    // stage x strip (w0-1 .. w0+64), zero-padded
    for (int s = tid; s < 66; s += 256) {
        int w = w0 - 1 + s;
        xs[s] = (w >= 0 && w < kW) ? x[((size_t)b * kH + t) * kW + w] : 0.0f;
    }
    // stage h slab: rows w0-1..w0+64, 128 ch bf16, XOR-swizzled 16B slots
    if (!FIRST) {
        for (int s = tid; s < 66 * 16; s += 256) {
            int row = s >> 4, col = s & 15;
            int w = w0 - 1 + row;
            short8v v = {0, 0, 0, 0, 0, 0, 0, 0};
            if (w >= 0 && w < kW) {
                v = *reinterpret_cast<const short8v*>(
                    reinterpret_cast<const short*>(hprev) +
                    (((size_t)b * kW + w) * kCH + col * 8));
            }
            int slot = col ^ (row & 7);
            *reinterpret_cast<short8v*>(Alds + row * 128 + slot * 8) = v;
        }
    }
    __syncthreads();

    float4v acc[4][4];  // [mfrag][gate]
#pragma unroll
    for (int mf = 0; mf < 4; ++mf)
#pragma unroll
        for (int g = 0; g < 4; ++g)
            acc[mf][g] = float4v{0.0f, 0.0f, 0.0f, 0.0f};

    const int ncol = lane & 15;
    const int krow = lane >> 4;          // 0..3
    const int ch16 = cht * 64 + wave * 16;

    if (!FIRST) {
#pragma unroll
        for (int kx = 0; kx < 3; ++kx) {
#pragma unroll
            for (int ks = 0; ks < 4; ++ks) {
                short8v bfr[4];
#pragma unroll
                for (int g = 0; g < 4; ++g) {
                    int n = g * 128 + ch16 + ncol;
                    bfr[g] = *reinterpret_cast<const short8v*>(
                        Bp + (((size_t)kx * 512 + n) * 128 + ks * 32 + krow * 8));
                }
#pragma unroll
                for (int mf = 0; mf < 4; ++mf) {
                    int srow = mf * 16 + ncol + kx;
                    int slot = (ks * 4 + krow) ^ (srow & 7);
                    short8v afr = *reinterpret_cast<const short8v*>(
                        Alds + srow * 128 + slot * 8);
#pragma unroll
                    for (int g = 0; g < 4; ++g)
                        acc[mf][g] = __builtin_amdgcn_mfma_f32_16x16x32_bf16(
                            afr, bfr[g], acc[mf][g], 0, 0, 0);
                }
            }
        }
    }

    // epilogue: bias + x-conv + gates + state update (all per-lane local)
    const int chg = ch16 + ncol;  // 0..127
    float wxk[4][3], bia[4];
#pragma unroll
    for (int g = 0; g < 4; ++g) {
        bia[g] = pb[g * 128 + chg];
#pragma unroll
        for (int kx = 0; kx < 3; ++kx)
            wxk[g][kx] = pxw[kx * 512 + g * 128 + chg];
    }

#pragma unroll
    for (int mf = 0; mf < 4; ++mf) {
#pragma unroll
        for (int r = 0; r < 4; ++r) {
            int m = mf * 16 + krow * 4 + r;
            float xm = xs[m], xc = xs[m + 1], xp = xs[m + 2];
            float v[4];
#pragma unroll
            for (int g = 0; g < 4; ++g)
                v[g] = acc[mf][g][r] + bia[g]
                     + xm * wxk[g][0] + xc * wxk[g][1] + xp * wxk[g][2];
            size_t idx = ((size_t)b * kW + (w0 + m)) * kCH + chg;
            float cprev = FIRST ? 0.0f : c[idx];
            float si = fsig(v[0]);
            float sf = fsig(v[1]);
            float tg = ftanh(v[2]);
            float so = fsig(v[3]);
            float cn = sf * cprev + si * tg;
            float hn = so * ftanh(cn);
            c[idx] = cn;
            hnext[idx] = __float2bfloat16(hn);
        }
    }
}

// ---------------------------------------------------------------------------
// Mean over W + Linear(CH->NC). grid = B, block = 256.
// ---------------------------------------------------------------------------
__global__ __launch_bounds__(256) void pool_fc(
    const __hip_bfloat16* __restrict__ h,  // [B][W][CH]
    const float* __restrict__ fc_w,        // [NC][CH]
    const float* __restrict__ fc_b,        // [NC]
    float* __restrict__ out)               // [B][NC]
{
    __shared__ float part[256];
    __shared__ float pooled[kCH];
    const int b = blockIdx.x, tid = threadIdx.x;
    const int ch = tid & 127, half = tid >> 7;
    float s = 0.0f;
    for (int w = half * 256; w < half * 256 + 256; ++w)
        s += __bfloat162float(h[((size_t)b * kW + w) * kCH + ch]);
    part[tid] = s;
    __syncthreads();
    if (tid < kCH) pooled[tid] = (part[tid] + part[tid + 128]) * (1.0f / kW);
    __syncthreads();
    if (tid < kNC) {
        float a = fc_b[tid];
        for (int k = 0; k < kCH; ++k)
            a = fmaf(pooled[k], fc_w[tid * kCH + k], a);
        out[b * kNC + tid] = a;
    }
}

// ---------------------------------------------------------------------------
extern "C" void kernel_launch(void* const* d_in, const int* in_sizes, int n_in,
                              void* d_out, int out_size, void* d_ws, size_t ws_size,
                              hipStream_t stream) {
    const float* x      = (const float*)d_in[0];
    const float* conv_w = (const float*)d_in[1];
    const float* conv_b = (const float*)d_in[2];
    const float* fc_w   = (const float*)d_in[3];
    const float* fc_b   = (const float*)d_in[4];
    float* out = (float*)d_out;

    const size_t stateN = (size_t)kB * kW * kCH;  // 4,194,304
    float* c            = (float*)d_ws;
    __hip_bfloat16* hA  = (__hip_bfloat16*)(c + stateN);
    __hip_bfloat16* hB  = hA + stateN;
    short* Bp           = (short*)(hB + stateN);   // 3*512*128
    float* pxw          = (float*)(Bp + 3 * 512 * 128);
    float* pb           = pxw + 3 * 512;

    pack_weights<<<768, 256, 0, stream>>>(conv_w, conv_b, Bp, pxw, pb);

    dim3 grid(kW / 64, 2, kB);
    dim3 block(256);
    // write(t) = (t&1) ? hA : hB ; read(t) = write(t-1)
    lstm_step<true><<<grid, block, 0, stream>>>(x, Bp, pxw, pb, hA, hB, c, 0);
    for (int t = 1; t < kH; ++t) {
        __hip_bfloat16* hp = (t & 1) ? hB : hA;
        __hip_bfloat16* hn = (t & 1) ? hA : hB;
        lstm_step<false><<<grid, block, 0, stream>>>(x, Bp, pxw, pb, hp, hn, c, t);
    }
    // t=127 wrote hA
    pool_fc<<<kB, 256, 0, stream>>>(hA, fc_w, fc_b, out);
}